// Round 1
// baseline (265.523 us; speedup 1.0000x reference)
//
#include <hip/hip_runtime.h>
#include <math.h>

#define DI __device__ __forceinline__

constexpr int BB  = 32;
constexpr int CC  = 128;
constexpr int NN  = 2048;
constexpr int HH  = 8;
constexpr int DKk = 16;
constexpr float INV_SCALE = 0.25f;   // 1/sqrt(DK)
constexpr float EPSf = 1e-5f;
constexpr int TN  = 64;              // n-columns per GEMM block
constexpr int CKc = 32;              // K-chunk

DI float sigmoidf_(float x){ return 1.0f / (1.0f + __expf(-x)); }

// ---------------------------------------------------------------------------
// K1: keysm[h,n,:] = softmax(memory[h,0,n,:] / 4)
// ---------------------------------------------------------------------------
__global__ void k_keysm(const float* __restrict__ mem, float* __restrict__ ks)
{
    const int row = blockIdx.x * 256 + threadIdx.x;      // h*NN + n, grid exact
    const float* p = mem + (size_t)row * DKk;
    float v[DKk];
    float mx = -1e30f;
#pragma unroll
    for (int q = 0; q < 4; q++) {
        float4 t = *(const float4*)(p + q * 4);
        v[q*4+0] = t.x * INV_SCALE; v[q*4+1] = t.y * INV_SCALE;
        v[q*4+2] = t.z * INV_SCALE; v[q*4+3] = t.w * INV_SCALE;
    }
#pragma unroll
    for (int k = 0; k < DKk; k++) mx = fmaxf(mx, v[k]);
    float s = 0.f;
#pragma unroll
    for (int k = 0; k < DKk; k++) { v[k] = __expf(v[k] - mx); s += v[k]; }
    const float inv = 1.0f / s;
    float* o = ks + (size_t)row * DKk;
#pragma unroll
    for (int q = 0; q < 4; q++) {
        float4 t;
        t.x = v[q*4+0]*inv; t.y = v[q*4+1]*inv; t.z = v[q*4+2]*inv; t.w = v[q*4+3]*inv;
        *(float4*)(o + q*4) = t;
    }
}

// ---------------------------------------------------------------------------
// Generic 128x128 GEMM over a 64-column tile.
// MODE 0: Y = relu(W X + b)
// MODE 1: t = relu(W X + b); Y = t*SW + SB + t + E0;  stats += (sum, sumsq)
// MODE 2: t = (W X + b) + E0; Y = t*SW + SB + t;      stats += (sum, sumsq)
// In-place (Y aliasing X) is safe: each block reads only its own columns and
// writes only after all chunk loads complete.
// ---------------------------------------------------------------------------
template<int MODE>
__global__ __launch_bounds__(256) void k_gemm(
    const float* __restrict__ X, const float* __restrict__ W,
    const float* __restrict__ bias, float* __restrict__ Y,
    const float* __restrict__ E0, const float* __restrict__ SW,
    const float* __restrict__ SB, float* __restrict__ stats)
{
    __shared__ float wt[CKc][132];   // wt[c][o], pad 132 -> conflict-light
    __shared__ float xs[CKc][68];    // xs[c][n]
    __shared__ float red[8];

    const int b  = blockIdx.x >> 5;            // NN/TN == 32 tiles per batch
    const int n0 = (blockIdx.x & 31) * TN;
    const int tid = threadIdx.x;
    const int ng = tid & 15, og = tid >> 4;    // 4 n, 8 o per thread

    float acc[8][4];
#pragma unroll
    for (int j = 0; j < 8; j++)
#pragma unroll
        for (int i = 0; i < 4; i++) acc[j][i] = 0.f;

    const float* xb = X + (size_t)b * CC * NN + n0;

    for (int c0 = 0; c0 < CC; c0 += CKc) {
        {   // stage W chunk transposed
            const int c = tid & 31, ob = tid >> 5;
#pragma unroll
            for (int r = 0; r < 16; r++) {
                const int o = ob + r * 8;
                wt[c][o] = W[o * CC + c0 + c];
            }
        }
        {   // stage X chunk
            const int c = tid >> 3, nq = tid & 7;
            const float* p = xb + (size_t)(c0 + c) * NN + nq * 8;
            float4 v0 = *(const float4*)p;
            float4 v1 = *(const float4*)(p + 4);
            *(float4*)&xs[c][nq*8]     = v0;
            *(float4*)&xs[c][nq*8 + 4] = v1;
        }
        __syncthreads();
#pragma unroll
        for (int c = 0; c < CKc; c++) {
            float xv[4], wv[8];
            *(float4*)xv       = *(const float4*)&xs[c][ng * 4];
            *(float4*)wv       = *(const float4*)&wt[c][og * 8];
            *(float4*)(wv + 4) = *(const float4*)&wt[c][og * 8 + 4];
#pragma unroll
            for (int j = 0; j < 8; j++)
#pragma unroll
                for (int i = 0; i < 4; i++)
                    acc[j][i] = fmaf(wv[j], xv[i], acc[j][i]);
        }
        __syncthreads();
    }

    float* yb = Y + (size_t)b * CC * NN + n0;
    float sum = 0.f, ssq = 0.f;
#pragma unroll
    for (int j = 0; j < 8; j++) {
        const int o = og * 8 + j;
        const float bv = bias[o];
        float tmp[4];
#pragma unroll
        for (int i = 0; i < 4; i++) {
            const int n = n0 + ng * 4 + i;
            const float a = acc[j][i] + bv;
            if (MODE == 0) {
                tmp[i] = fmaxf(a, 0.f);
            } else if (MODE == 1) {
                const float t = fmaxf(a, 0.f);
                const float y = t * SW[(size_t)o * NN + n] + SB[(size_t)o * NN + n]
                              + t + E0[(size_t)b * CC * NN + (size_t)o * NN + n];
                sum += y; ssq += y * y;
                tmp[i] = y;
            } else {
                const float t = a + E0[(size_t)b * CC * NN + (size_t)o * NN + n];
                const float y = t * SW[(size_t)o * NN + n] + SB[(size_t)o * NN + n] + t;
                sum += y; ssq += y * y;
                tmp[i] = y;
            }
        }
        float4 r; r.x = tmp[0]; r.y = tmp[1]; r.z = tmp[2]; r.w = tmp[3];
        *(float4*)(yb + (size_t)o * NN + ng * 4) = r;
    }

    if (MODE == 1 || MODE == 2) {
#pragma unroll
        for (int off = 32; off > 0; off >>= 1) {
            sum += __shfl_down(sum, off);
            ssq += __shfl_down(ssq, off);
        }
        const int wid = tid >> 6;
        if ((tid & 63) == 0) { red[wid * 2] = sum; red[wid * 2 + 1] = ssq; }
        __syncthreads();
        if (tid == 0) {
            float s = 0.f, q = 0.f;
#pragma unroll
            for (int w = 0; w < 4; w++) { s += red[w * 2]; q += red[w * 2 + 1]; }
            atomicAdd(&stats[2 * b],     s);
            atomicAdd(&stats[2 * b + 1], q);
        }
    }
}

// ---------------------------------------------------------------------------
// K4: kv[b,h,x,y] += sum_n keysm[h,n,x] * v[b, 16h+y, n]   (8-way n split)
// ---------------------------------------------------------------------------
__global__ __launch_bounds__(256) void k_kv(
    const float* __restrict__ ks, const float* __restrict__ V, float* __restrict__ kv)
{
    constexpr int SPLIT = 8;
    const int bid = blockIdx.x;
    const int seg = bid % SPLIT;
    const int h   = (bid / SPLIT) % HH;
    const int b   = bid / (SPLIT * HH);
    __shared__ float kt[64][16];
    __shared__ float vt[16][68];
    const int tid = threadIdx.x;
    const int x = tid & 15, y = tid >> 4;
    float acc = 0.f;
    const float* ksb = ks + (size_t)h * NN * DKk;
    const float* vb  = V + ((size_t)b * CC + h * DKk) * NN;
    const int nbeg = seg * (NN / SPLIT);
    for (int n0 = nbeg; n0 < nbeg + NN / SPLIT; n0 += 64) {
        {
            const int i = tid >> 2, q = tid & 3;
            *(float4*)&kt[i][q * 4] = *(const float4*)&ksb[(size_t)(n0 + i) * DKk + q * 4];
        }
        {
            const int y2 = tid >> 4, nq = tid & 15;
            *(float4*)&vt[y2][nq * 4] = *(const float4*)&vb[(size_t)y2 * NN + n0 + nq * 4];
        }
        __syncthreads();
#pragma unroll
        for (int i = 0; i < 64; i++)
            acc = fmaf(kt[i][x], vt[y][i], acc);
        __syncthreads();
    }
    atomicAdd(&kv[(((size_t)(b * HH + h)) * DKk + x) * DKk + y], acc);
}

// ---------------------------------------------------------------------------
// K5: per (b,h,n): query = softmax(q/4); xcat = query . kv[b,h] + v (in-place V)
// ---------------------------------------------------------------------------
__global__ __launch_bounds__(256) void k_attn(
    const float* __restrict__ Q, const float* __restrict__ kv, float* __restrict__ VX)
{
    const int bid = blockIdx.x;
    const int nchunks = NN / 256;                // 8
    const int b = bid / (HH * nchunks);
    const int r = bid % (HH * nchunks);
    const int h = r / nchunks;
    const int n0 = (r % nchunks) * 256;
    __shared__ float kvl[DKk * DKk];
    const int tid = threadIdx.x;
    kvl[tid] = kv[(size_t)(b * HH + h) * DKk * DKk + tid];
    __syncthreads();
    const int n = n0 + tid;
    const float* qb = Q + ((size_t)b * CC + h * DKk) * NN + n;
    float q[DKk];
    float mx = -1e30f;
#pragma unroll
    for (int k = 0; k < DKk; k++) {
        q[k] = qb[(size_t)k * NN] * INV_SCALE;
        mx = fmaxf(mx, q[k]);
    }
    float s = 0.f;
#pragma unroll
    for (int k = 0; k < DKk; k++) { q[k] = __expf(q[k] - mx); s += q[k]; }
    const float inv = 1.0f / s;
#pragma unroll
    for (int k = 0; k < DKk; k++) q[k] *= inv;
    float* vb = VX + ((size_t)b * CC + h * DKk) * NN + n;
#pragma unroll
    for (int y = 0; y < DKk; y++) {
        float a = 0.f;
#pragma unroll
        for (int x = 0; x < DKk; x++) a = fmaf(q[x], kvl[x * DKk + y], a);
        vb[(size_t)y * NN] = a + vb[(size_t)y * NN];
    }
}

// ---------------------------------------------------------------------------
// K7: xn = (y - m1)/sd1 (in-place);  G = (Wg1 xn + b1) * sigmoid(Wg2 xn + b2)
// ---------------------------------------------------------------------------
__global__ __launch_bounds__(256) void k_glu12(
    float* __restrict__ Yx,
    const float* __restrict__ W1, const float* __restrict__ b1,
    const float* __restrict__ W2, const float* __restrict__ b2,
    const float* __restrict__ stats1, float* __restrict__ G)
{
    __shared__ float wt1[CKc][132];
    __shared__ float wt2[CKc][132];
    __shared__ float xs[CKc][68];
    const int b  = blockIdx.x >> 5;
    const int n0 = (blockIdx.x & 31) * TN;
    const float mean = stats1[2 * b] * (1.0f / (CC * NN));
    const float var  = stats1[2 * b + 1] * (1.0f / (CC * NN)) - mean * mean;
    const float inv  = rsqrtf(var + EPSf);
    const int tid = threadIdx.x;
    const int ng = tid & 15, og = tid >> 4;
    float a1[8][4], a2[8][4];
#pragma unroll
    for (int j = 0; j < 8; j++)
#pragma unroll
        for (int i = 0; i < 4; i++) { a1[j][i] = 0.f; a2[j][i] = 0.f; }

    float* yb = Yx + (size_t)b * CC * NN + n0;
    for (int c0 = 0; c0 < CC; c0 += CKc) {
        {
            const int c = tid & 31, ob = tid >> 5;
#pragma unroll
            for (int r = 0; r < 16; r++) {
                const int o = ob + r * 8;
                wt1[c][o] = W1[o * CC + c0 + c];
                wt2[c][o] = W2[o * CC + c0 + c];
            }
        }
        {
            const int c = tid >> 3, nq = tid & 7;
            float* p = yb + (size_t)(c0 + c) * NN + nq * 8;
            float4 v0 = *(const float4*)p;
            float4 v1 = *(const float4*)(p + 4);
            v0.x = (v0.x - mean) * inv; v0.y = (v0.y - mean) * inv;
            v0.z = (v0.z - mean) * inv; v0.w = (v0.w - mean) * inv;
            v1.x = (v1.x - mean) * inv; v1.y = (v1.y - mean) * inv;
            v1.z = (v1.z - mean) * inv; v1.w = (v1.w - mean) * inv;
            *(float4*)p       = v0;      // write xn back in place
            *(float4*)(p + 4) = v1;
            *(float4*)&xs[c][nq*8]     = v0;
            *(float4*)&xs[c][nq*8 + 4] = v1;
        }
        __syncthreads();
#pragma unroll
        for (int c = 0; c < CKc; c++) {
            float xv[4], w1v[8], w2v[8];
            *(float4*)xv        = *(const float4*)&xs[c][ng * 4];
            *(float4*)w1v       = *(const float4*)&wt1[c][og * 8];
            *(float4*)(w1v + 4) = *(const float4*)&wt1[c][og * 8 + 4];
            *(float4*)w2v       = *(const float4*)&wt2[c][og * 8];
            *(float4*)(w2v + 4) = *(const float4*)&wt2[c][og * 8 + 4];
#pragma unroll
            for (int j = 0; j < 8; j++)
#pragma unroll
                for (int i = 0; i < 4; i++) {
                    a1[j][i] = fmaf(w1v[j], xv[i], a1[j][i]);
                    a2[j][i] = fmaf(w2v[j], xv[i], a2[j][i]);
                }
        }
        __syncthreads();
    }
    float* gb = G + (size_t)b * CC * NN + n0;
#pragma unroll
    for (int j = 0; j < 8; j++) {
        const int o = og * 8 + j;
        const float c1b = b1[o], c2b = b2[o];
        float tmp[4];
#pragma unroll
        for (int i = 0; i < 4; i++)
            tmp[i] = (a1[j][i] + c1b) * sigmoidf_(a2[j][i] + c2b);
        float4 rr; rr.x = tmp[0]; rr.y = tmp[1]; rr.z = tmp[2]; rr.w = tmp[3];
        *(float4*)(gb + (size_t)o * NN + ng * 4) = rr;
    }
}

// ---------------------------------------------------------------------------
// K9: out = (x2 - m2)/sd2
// ---------------------------------------------------------------------------
__global__ void k_lnfin(const float* __restrict__ X2, const float* __restrict__ stats2,
                        float* __restrict__ out)
{
    const size_t i4 = (size_t)blockIdx.x * 256 + threadIdx.x;
    const size_t idx = i4 * 4;
    const int b = (int)(idx / ((size_t)CC * NN));
    const float mean = stats2[2 * b] * (1.0f / (CC * NN));
    const float var  = stats2[2 * b + 1] * (1.0f / (CC * NN)) - mean * mean;
    const float inv  = rsqrtf(var + EPSf);
    float4 v = *(const float4*)(X2 + idx);
    v.x = (v.x - mean) * inv; v.y = (v.y - mean) * inv;
    v.z = (v.z - mean) * inv; v.w = (v.w - mean) * inv;
    *(float4*)(out + idx) = v;
}

// ---------------------------------------------------------------------------
extern "C" void kernel_launch(void* const* d_in, const int* in_sizes, int n_in,
                              void* d_out, int out_size, void* d_ws, size_t ws_size,
                              hipStream_t stream)
{
    const float* input = (const float*)d_in[0];
    const float* Wq  = (const float*)d_in[1];
    const float* bq  = (const float*)d_in[2];
    const float* Wv  = (const float*)d_in[3];
    const float* bv  = (const float*)d_in[4];
    const float* Wc  = (const float*)d_in[5];
    const float* bc  = (const float*)d_in[6];
    const float* mem = (const float*)d_in[7];
    const float* saw = (const float*)d_in[8];
    const float* sab = (const float*)d_in[9];
    // d_in[10], d_in[11] (nodevec1/2) are provably unused:
    // attn_dyn = rowsum(softmax(.)) * value = value exactly.
    const float* Wg1 = (const float*)d_in[12];
    const float* bg1 = (const float*)d_in[13];
    const float* Wg2 = (const float*)d_in[14];
    const float* bg2 = (const float*)d_in[15];
    const float* Wg3 = (const float*)d_in[16];
    const float* bg3 = (const float*)d_in[17];
    float* out = (float*)d_out;

    const size_t BCN = (size_t)BB * CC * NN;
    float* ws    = (float*)d_ws;
    float* buf1  = ws;
    float* keysm = buf1 + BCN;
    float* kvb   = keysm + (size_t)HH * NN * DKk;
    float* stats = kvb + (size_t)BB * HH * DKk * DKk;    // 4*BB floats
    float* after = stats + 4 * BB;
    const size_t base_floats = (size_t)(after - ws);
    float* buf2 = (ws_size >= (base_floats + BCN) * sizeof(float)) ? after : out;

    hipMemsetAsync(kvb, 0, ((size_t)BB * HH * DKk * DKk + 4 * BB) * sizeof(float), stream);

    k_keysm<<<HH * NN / 256, 256, 0, stream>>>(mem, keysm);
    k_gemm<0><<<BB * 32, 256, 0, stream>>>(input, Wv, bv, buf1, nullptr, nullptr, nullptr, nullptr);
    k_gemm<0><<<BB * 32, 256, 0, stream>>>(input, Wq, bq, buf2, nullptr, nullptr, nullptr, nullptr);
    k_kv<<<BB * HH * 8, 256, 0, stream>>>(keysm, buf1, kvb);
    k_attn<<<BB * HH * (NN / 256), 256, 0, stream>>>(buf2, kvb, buf1);
    k_gemm<1><<<BB * 32, 256, 0, stream>>>(buf1, Wc, bc, buf1, input, saw, sab, stats);
    k_glu12<<<BB * 32, 256, 0, stream>>>(buf1, Wg1, bg1, Wg2, bg2, stats, buf2);
    k_gemm<2><<<BB * 32, 256, 0, stream>>>(buf2, Wg3, bg3, buf2, buf1, saw, sab, stats + 2 * BB);
    k_lnfin<<<(unsigned)(BCN / 1024), 256, 0, stream>>>(buf2, stats + 2 * BB, out);
}

// Round 2
// 143.819 us; speedup vs baseline: 1.8462x; 1.8462x over previous
//
#include <hip/hip_runtime.h>
#include <math.h>

#define DI __device__ __forceinline__

typedef short bf16x8 __attribute__((ext_vector_type(8)));
typedef float f32x4 __attribute__((ext_vector_type(4)));

constexpr int BB = 32, CC = 128, NN = 2048, HH = 8;
constexpr float EPSf = 1e-5f;
constexpr float RCN = 1.0f / (CC * (float)NN);

#define MFMA(a,b,c) __builtin_amdgcn_mfma_f32_16x16x32_bf16(a,b,c,0,0,0)

DI unsigned short f2b(float f){
    union { float f; unsigned u; } v; v.f = f;
    return (unsigned short)((v.u + 0x7FFFu + ((v.u >> 16) & 1u)) >> 16);
}
DI float b2f(unsigned short h){
    union { unsigned u; float f; } v; v.u = ((unsigned)h) << 16;
    return v.f;
}
DI float sigm(float x){ return 1.0f / (1.0f + __expf(-x)); }

// ---------------------------------------------------------------------------
// K1: ksT[h][x][n] = softmax_x(memory[h,0,n,:]/4)  transposed, bf16
// ---------------------------------------------------------------------------
__global__ __launch_bounds__(256) void k_keysm(const float* __restrict__ mem,
                                               unsigned short* __restrict__ ksT)
{
    const int row = blockIdx.x * 256 + threadIdx.x;   // h*NN + n
    const int h = row >> 11, n = row & 2047;
    const float* p = mem + (size_t)row * 16;
    float v[16];
    f32x4 t0 = *(const f32x4*)(p);
    f32x4 t1 = *(const f32x4*)(p + 4);
    f32x4 t2 = *(const f32x4*)(p + 8);
    f32x4 t3 = *(const f32x4*)(p + 12);
#pragma unroll
    for (int j = 0; j < 4; j++) { v[j] = t0[j]; v[4+j] = t1[j]; v[8+j] = t2[j]; v[12+j] = t3[j]; }
    float mx = v[0];
#pragma unroll
    for (int x = 1; x < 16; x++) mx = fmaxf(mx, v[x]);
    float s = 0.f;
#pragma unroll
    for (int x = 0; x < 16; x++) { v[x] = __expf((v[x] - mx) * 0.25f); s += v[x]; }
    const float is = 1.0f / s;
#pragma unroll
    for (int x = 0; x < 16; x++)
        ksT[((size_t)(h * 16 + x)) * NN + n] = f2b(v[x] * is);
}

// ---------------------------------------------------------------------------
// K2: fused Q,V GEMM.  qT/vT[b][n][c] bf16 = relu(W X + b)
// A = W (LDS bf16, padded), B = input f32 [b][c][n] via strided loads + cvt
// ---------------------------------------------------------------------------
__global__ __launch_bounds__(256,2) void k_qv(
    const float* __restrict__ in, const float* __restrict__ Wq, const float* __restrict__ bq,
    const float* __restrict__ Wv, const float* __restrict__ bv,
    unsigned short* __restrict__ qT, unsigned short* __restrict__ vT)
{
    __shared__ unsigned short Wa[128*136];
    __shared__ unsigned short Wb[128*136];
    const int b = blockIdx.x >> 4;
    const int n0 = (blockIdx.x & 15) * 128;
    const int tid = threadIdx.x;
#pragma unroll
    for (int r = 0; r < 16; r++) {
        const int i4 = r * 256 + tid, o = i4 >> 5, cq = i4 & 31;
        f32x4 w1 = *(const f32x4*)&Wq[o*128 + cq*4];
        f32x4 w2 = *(const f32x4*)&Wv[o*128 + cq*4];
        ushort4 p1, p2;
        p1.x=f2b(w1[0]); p1.y=f2b(w1[1]); p1.z=f2b(w1[2]); p1.w=f2b(w1[3]);
        p2.x=f2b(w2[0]); p2.y=f2b(w2[1]); p2.z=f2b(w2[2]); p2.w=f2b(w2[3]);
        *(ushort4*)&Wa[o*136 + cq*4] = p1;
        *(ushort4*)&Wb[o*136 + cq*4] = p2;
    }
    __syncthreads();
    const int l = tid & 63, wid = tid >> 6;
    const int wo = wid & 1, wn = wid >> 1;
    const int lr = l & 15, lg = l >> 4;
    f32x4 accq[4][4], accv[4][4];
    const f32x4 z = {0.f,0.f,0.f,0.f};
#pragma unroll
    for (int i = 0; i < 4; i++)
#pragma unroll
        for (int j = 0; j < 4; j++) { accq[i][j] = z; accv[i][j] = z; }
    const float* inb = in + (size_t)b * CC * NN;
#pragma unroll
    for (int ks = 0; ks < 4; ks++) {
        const int cb = ks*32 + lg*8;
        bf16x8 aq[4], av[4];
#pragma unroll
        for (int mf = 0; mf < 4; mf++) {
            const int o = wo*64 + mf*16 + lr;
            aq[mf] = *(const bf16x8*)&Wa[o*136 + cb];
            av[mf] = *(const bf16x8*)&Wb[o*136 + cb];
        }
        bf16x8 bx[4];
#pragma unroll
        for (int nf = 0; nf < 4; nf++) {
            const int n = n0 + wn*64 + nf*16 + lr;
            union { bf16x8 v; unsigned short u[8]; } t;
#pragma unroll
            for (int j = 0; j < 8; j++) t.u[j] = f2b(inb[(size_t)(cb + j) * NN + n]);
            bx[nf] = t.v;
        }
#pragma unroll
        for (int mf = 0; mf < 4; mf++)
#pragma unroll
            for (int nf = 0; nf < 4; nf++) {
                accq[mf][nf] = MFMA(aq[mf], bx[nf], accq[mf][nf]);
                accv[mf][nf] = MFMA(av[mf], bx[nf], accv[mf][nf]);
            }
    }
#pragma unroll
    for (int mf = 0; mf < 4; mf++) {
        const int ob = wo*64 + mf*16 + lg*4;
        const f32x4 bq4 = *(const f32x4*)&bq[ob];
        const f32x4 bv4 = *(const f32x4*)&bv[ob];
#pragma unroll
        for (int nf = 0; nf < 4; nf++) {
            const int n = n0 + wn*64 + nf*16 + lr;
            const size_t yo = ((size_t)b * NN + n) * CC + ob;
            f32x4 aq_ = accq[mf][nf], av_ = accv[mf][nf];
            ushort4 pq, pv;
            pq.x = f2b(fmaxf(aq_[0]+bq4[0],0.f)); pq.y = f2b(fmaxf(aq_[1]+bq4[1],0.f));
            pq.z = f2b(fmaxf(aq_[2]+bq4[2],0.f)); pq.w = f2b(fmaxf(aq_[3]+bq4[3],0.f));
            pv.x = f2b(fmaxf(av_[0]+bv4[0],0.f)); pv.y = f2b(fmaxf(av_[1]+bv4[1],0.f));
            pv.z = f2b(fmaxf(av_[2]+bv4[2],0.f)); pv.w = f2b(fmaxf(av_[3]+bv4[3],0.f));
            *(ushort4*)&qT[yo] = pq;
            *(ushort4*)&vT[yo] = pv;
        }
    }
}

// ---------------------------------------------------------------------------
// K3: kv[b,h,x,y] = sum_n ksT[h,x,n]*vT[b,n,h16+y]  (MFMA, per-wave n-segment)
// ---------------------------------------------------------------------------
__global__ __launch_bounds__(256) void k_kv(const unsigned short* __restrict__ ksT,
                                            const unsigned short* __restrict__ vT,
                                            float* __restrict__ kvb)
{
    __shared__ unsigned short vt[4 * 16 * 520];
    const int bh = blockIdx.x;
    const int b = bh >> 3, h = bh & 7;
    const int tid = threadIdx.x, l = tid & 63, wid = tid >> 6;
    const int n0 = wid * 512;
    unsigned short* vtw = vt + wid * (16 * 520);
    const unsigned short* vb = vT + ((size_t)b * NN + n0) * CC + h * 16;
#pragma unroll
    for (int r = 0; r < 8; r++) {
        const int nl = r * 64 + l;
        ushort4 p0 = *(const ushort4*)&vb[(size_t)nl * CC + 0];
        ushort4 p1 = *(const ushort4*)&vb[(size_t)nl * CC + 4];
        ushort4 p2 = *(const ushort4*)&vb[(size_t)nl * CC + 8];
        ushort4 p3 = *(const ushort4*)&vb[(size_t)nl * CC + 12];
        vtw[ 0*520+nl]=p0.x; vtw[ 1*520+nl]=p0.y; vtw[ 2*520+nl]=p0.z; vtw[ 3*520+nl]=p0.w;
        vtw[ 4*520+nl]=p1.x; vtw[ 5*520+nl]=p1.y; vtw[ 6*520+nl]=p1.z; vtw[ 7*520+nl]=p1.w;
        vtw[ 8*520+nl]=p2.x; vtw[ 9*520+nl]=p2.y; vtw[10*520+nl]=p2.z; vtw[11*520+nl]=p2.w;
        vtw[12*520+nl]=p3.x; vtw[13*520+nl]=p3.y; vtw[14*520+nl]=p3.z; vtw[15*520+nl]=p3.w;
    }
    const int lr = l & 15, lg = l >> 4;
    const unsigned short* ka = ksT + (size_t)h * 16 * NN;
    f32x4 acc = {0.f,0.f,0.f,0.f};
#pragma unroll
    for (int kk = 0; kk < 16; kk++) {
        bf16x8 af = *(const bf16x8*)&ka[(size_t)lr * NN + n0 + kk*32 + lg*8];
        bf16x8 bf = *(const bf16x8*)&vtw[lr * 520 + kk*32 + lg*8];
        acc = MFMA(af, bf, acc);
    }
    float* kp = kvb + ((size_t)(b * 8 + h)) * 256;
#pragma unroll
    for (int r = 0; r < 4; r++)
        atomicAdd(&kp[(lg*4 + r) * 16 + lr], acc[r]);
}

// ---------------------------------------------------------------------------
// K4: per (b,n,h): p = softmax(q/4); out = p.kv + v  (in-place into qT)
// ---------------------------------------------------------------------------
__global__ __launch_bounds__(256) void k_attn(unsigned short* __restrict__ qT,
                                              const unsigned short* __restrict__ vT,
                                              const float* __restrict__ kvb)
{
    __shared__ float kvl[8 * 260];
    const int b = blockIdx.x >> 6, nb = blockIdx.x & 63;
    const int tid = threadIdx.x;
    {
        const float* kp = kvb + (size_t)b * 2048 + (tid >> 5) * 256 + (tid & 31) * 8;
        f32x4 v0 = *(const f32x4*)kp;
        f32x4 v1 = *(const f32x4*)(kp + 4);
        float* dst = &kvl[(tid >> 5) * 260 + (tid & 31) * 8];
        *(f32x4*)dst = v0; *(f32x4*)(dst + 4) = v1;
    }
    __syncthreads();
    const int h = tid & 7, nl = tid >> 3;
    const int n = nb * 32 + nl;
    unsigned short* qp = qT + ((size_t)b * NN + n) * CC + h * 16;
    const unsigned short* vp = vT + ((size_t)b * NN + n) * CC + h * 16;
    float q[16];
    {
        uint4 u0 = *(const uint4*)qp, u1 = *(const uint4*)(qp + 8);
        unsigned uu[8] = {u0.x,u0.y,u0.z,u0.w,u1.x,u1.y,u1.z,u1.w};
#pragma unroll
        for (int j = 0; j < 8; j++) {
            q[2*j]   = b2f((unsigned short)(uu[j] & 0xffffu));
            q[2*j+1] = b2f((unsigned short)(uu[j] >> 16));
        }
    }
    float mx = q[0];
#pragma unroll
    for (int x = 1; x < 16; x++) mx = fmaxf(mx, q[x]);
    float p[16]; float s = 0.f;
#pragma unroll
    for (int x = 0; x < 16; x++) { p[x] = __expf((q[x] - mx) * 0.25f); s += p[x]; }
    const float is = 1.0f / s;
    const float* kh = &kvl[h * 260];
    float r[16];
#pragma unroll
    for (int y = 0; y < 16; y++) r[y] = 0.f;
#pragma unroll
    for (int x = 0; x < 16; x++) {
        const float px = p[x];
#pragma unroll
        for (int y = 0; y < 16; y++) r[y] = fmaf(px, kh[x * 16 + y], r[y]);
    }
    unsigned w[8];
    {
        uint4 u0 = *(const uint4*)vp, u1 = *(const uint4*)(vp + 8);
        unsigned uu[8] = {u0.x,u0.y,u0.z,u0.w,u1.x,u1.y,u1.z,u1.w};
#pragma unroll
        for (int j = 0; j < 8; j++) {
            float o0 = r[2*j]   * is + b2f((unsigned short)(uu[j] & 0xffffu));
            float o1 = r[2*j+1] * is + b2f((unsigned short)(uu[j] >> 16));
            w[j] = (unsigned)f2b(o0) | ((unsigned)f2b(o1) << 16);
        }
    }
    uint4 o0; o0.x=w[0]; o0.y=w[1]; o0.z=w[2]; o0.w=w[3];
    uint4 o1; o1.x=w[4]; o1.y=w[5]; o1.z=w[6]; o1.w=w[7];
    *(uint4*)qp = o0; *(uint4*)(qp + 8) = o1;
}

// ---------------------------------------------------------------------------
// K5/K7: single-W GEMM + epilogue.
// EPI 0 (Wc): t=relu(acc+b); y=t*sw+sb+t+input_f32; stats -> statsOut
// EPI 1 (Wg3): xn=(e0-m)*inv; t=acc+b+xn; y=t*sw+sb+t; stats -> statsOut
// ---------------------------------------------------------------------------
template<int EPI>
__global__ __launch_bounds__(256,2) void k_gemmC(
    const unsigned short* __restrict__ act, const float* __restrict__ W,
    const float* __restrict__ bias, const float* __restrict__ saw,
    const float* __restrict__ sab, const float* __restrict__ in0f,
    const unsigned short* __restrict__ e0b, const float* __restrict__ statsIn,
    float* __restrict__ statsOut, unsigned short* __restrict__ Y)
{
    __shared__ unsigned short Wl[128*136];
    __shared__ float red[8];
    const int b = blockIdx.x >> 4;
    const int n0 = (blockIdx.x & 15) * 128;
    const int tid = threadIdx.x;
    float mean = 0.f, inv = 0.f;
    if (EPI == 1) {
        mean = statsIn[2*b] * RCN;
        const float var = statsIn[2*b+1] * RCN - mean * mean;
        inv = rsqrtf(var + EPSf);
    }
#pragma unroll
    for (int r = 0; r < 16; r++) {
        const int i4 = r * 256 + tid, o = i4 >> 5, cq = i4 & 31;
        f32x4 w1 = *(const f32x4*)&W[o*128 + cq*4];
        ushort4 p1;
        p1.x=f2b(w1[0]); p1.y=f2b(w1[1]); p1.z=f2b(w1[2]); p1.w=f2b(w1[3]);
        *(ushort4*)&Wl[o*136 + cq*4] = p1;
    }
    __syncthreads();
    const int l = tid & 63, wid = tid >> 6;
    const int wo = wid & 1, wn = wid >> 1;
    const int lr = l & 15, lg = l >> 4;
    f32x4 acc[4][4];
    const f32x4 z = {0.f,0.f,0.f,0.f};
#pragma unroll
    for (int i = 0; i < 4; i++)
#pragma unroll
        for (int j = 0; j < 4; j++) acc[i][j] = z;
    const unsigned short* ab = act + (size_t)b * NN * CC;
#pragma unroll
    for (int ks = 0; ks < 4; ks++) {
        const int cb = ks*32 + lg*8;
        bf16x8 af[4];
#pragma unroll
        for (int mf = 0; mf < 4; mf++)
            af[mf] = *(const bf16x8*)&Wl[(wo*64 + mf*16 + lr)*136 + cb];
        bf16x8 bx[4];
#pragma unroll
        for (int nf = 0; nf < 4; nf++)
            bx[nf] = *(const bf16x8*)&ab[(size_t)(n0 + wn*64 + nf*16 + lr) * CC + cb];
#pragma unroll
        for (int mf = 0; mf < 4; mf++)
#pragma unroll
            for (int nf = 0; nf < 4; nf++)
                acc[mf][nf] = MFMA(af[mf], bx[nf], acc[mf][nf]);
    }
    float sum = 0.f, ssq = 0.f;
#pragma unroll
    for (int mf = 0; mf < 4; mf++) {
        const int ob = wo*64 + mf*16 + lg*4;
        const f32x4 b4 = *(const f32x4*)&bias[ob];
#pragma unroll
        for (int nf = 0; nf < 4; nf++) {
            const int n = n0 + wn*64 + nf*16 + lr;
            const size_t yo = ((size_t)b * NN + n) * CC + ob;
            f32x4 a = acc[mf][nf];
            ushort4 eu;
            if (EPI == 1) eu = *(const ushort4*)&e0b[yo];
            ushort4 pk;
            float ys[4];
#pragma unroll
            for (int r = 0; r < 4; r++) {
                const int o = ob + r;
                float t;
                if (EPI == 0) {
                    t = fmaxf(a[r] + b4[r], 0.f);
                } else {
                    const unsigned short ev = (r==0)?eu.x:(r==1)?eu.y:(r==2)?eu.z:eu.w;
                    t = a[r] + b4[r] + (b2f(ev) - mean) * inv;
                }
                const float sw = saw[(size_t)o * NN + n];
                const float sb = sab[(size_t)o * NN + n];
                float y = t * sw + sb + t;
                if (EPI == 0) y += in0f[((size_t)b * CC + o) * NN + n];
                sum += y; ssq += y * y;
                ys[r] = y;
            }
            pk.x = f2b(ys[0]); pk.y = f2b(ys[1]); pk.z = f2b(ys[2]); pk.w = f2b(ys[3]);
            *(ushort4*)&Y[yo] = pk;
        }
    }
#pragma unroll
    for (int off = 32; off > 0; off >>= 1) {
        sum += __shfl_down(sum, off);
        ssq += __shfl_down(ssq, off);
    }
    if ((tid & 63) == 0) { red[wid*2] = sum; red[wid*2+1] = ssq; }
    __syncthreads();
    if (tid == 0) {
        float s = red[0]+red[2]+red[4]+red[6];
        float q = red[1]+red[3]+red[5]+red[7];
        atomicAdd(&statsOut[2*b], s);
        atomicAdd(&statsOut[2*b+1], q);
    }
}

// ---------------------------------------------------------------------------
// K6: GLU double GEMM on normalized input, with LN folded into weights:
//   W.xn = inv*(W.y1) - inv*mean*rowsum(W);  G = g1*sigmoid(g2)
// ---------------------------------------------------------------------------
__global__ __launch_bounds__(256,2) void k_glu12(
    const unsigned short* __restrict__ y1, const float* __restrict__ W1,
    const float* __restrict__ b1, const float* __restrict__ W2,
    const float* __restrict__ b2, const float* __restrict__ stats1,
    unsigned short* __restrict__ G)
{
    __shared__ unsigned short Wl1[128*136];
    __shared__ unsigned short Wl2[128*136];
    __shared__ float cs[256];
    const int b = blockIdx.x >> 4;
    const int n0 = (blockIdx.x & 15) * 128;
    const int tid = threadIdx.x;
    const float mean = stats1[2*b] * RCN;
    const float var = stats1[2*b+1] * RCN - mean * mean;
    const float inv = rsqrtf(var + EPSf);
#pragma unroll
    for (int r = 0; r < 16; r++) {
        const int i4 = r * 256 + tid, o = i4 >> 5, cq = i4 & 31;
        f32x4 w1 = *(const f32x4*)&W1[o*128 + cq*4];
        f32x4 w2 = *(const f32x4*)&W2[o*128 + cq*4];
        ushort4 p1, p2;
        p1.x=f2b(w1[0]); p1.y=f2b(w1[1]); p1.z=f2b(w1[2]); p1.w=f2b(w1[3]);
        p2.x=f2b(w2[0]); p2.y=f2b(w2[1]); p2.z=f2b(w2[2]); p2.w=f2b(w2[3]);
        *(ushort4*)&Wl1[o*136 + cq*4] = p1;
        *(ushort4*)&Wl2[o*136 + cq*4] = p2;
    }
    {
        const int o = tid >> 1, hf = tid & 1;
        float s1 = 0.f, s2 = 0.f;
#pragma unroll
        for (int j4 = 0; j4 < 16; j4++) {
            f32x4 a = *(const f32x4*)&W1[o*128 + hf*64 + j4*4];
            f32x4 c = *(const f32x4*)&W2[o*128 + hf*64 + j4*4];
            s1 += a[0]+a[1]+a[2]+a[3];
            s2 += c[0]+c[1]+c[2]+c[3];
        }
        s1 += __shfl_xor(s1, 1);
        s2 += __shfl_xor(s2, 1);
        cs[o]       = b1[o] - mean * inv * s1;
        cs[128 + o] = b2[o] - mean * inv * s2;
    }
    __syncthreads();
    const int l = tid & 63, wid = tid >> 6;
    const int wo = wid & 1, wn = wid >> 1;
    const int lr = l & 15, lg = l >> 4;
    f32x4 acc1[4][4], acc2[4][4];
    const f32x4 z = {0.f,0.f,0.f,0.f};
#pragma unroll
    for (int i = 0; i < 4; i++)
#pragma unroll
        for (int j = 0; j < 4; j++) { acc1[i][j] = z; acc2[i][j] = z; }
    const unsigned short* ab = y1 + (size_t)b * NN * CC;
#pragma unroll
    for (int ks = 0; ks < 4; ks++) {
        const int cb = ks*32 + lg*8;
        bf16x8 a1[4], a2[4];
#pragma unroll
        for (int mf = 0; mf < 4; mf++) {
            const int o = wo*64 + mf*16 + lr;
            a1[mf] = *(const bf16x8*)&Wl1[o*136 + cb];
            a2[mf] = *(const bf16x8*)&Wl2[o*136 + cb];
        }
        bf16x8 bx[4];
#pragma unroll
        for (int nf = 0; nf < 4; nf++)
            bx[nf] = *(const bf16x8*)&ab[(size_t)(n0 + wn*64 + nf*16 + lr) * CC + cb];
#pragma unroll
        for (int mf = 0; mf < 4; mf++)
#pragma unroll
            for (int nf = 0; nf < 4; nf++) {
                acc1[mf][nf] = MFMA(a1[mf], bx[nf], acc1[mf][nf]);
                acc2[mf][nf] = MFMA(a2[mf], bx[nf], acc2[mf][nf]);
            }
    }
#pragma unroll
    for (int mf = 0; mf < 4; mf++) {
        const int ob = wo*64 + mf*16 + lg*4;
        const f32x4 c1 = *(const f32x4*)&cs[ob];
        const f32x4 c2 = *(const f32x4*)&cs[128 + ob];
#pragma unroll
        for (int nf = 0; nf < 4; nf++) {
            const int n = n0 + wn*64 + nf*16 + lr;
            const size_t yo = ((size_t)b * NN + n) * CC + ob;
            ushort4 pk;
            float g1, g2;
            g1 = acc1[mf][nf][0]*inv + c1[0]; g2 = acc2[mf][nf][0]*inv + c2[0];
            pk.x = f2b(g1 * sigm(g2));
            g1 = acc1[mf][nf][1]*inv + c1[1]; g2 = acc2[mf][nf][1]*inv + c2[1];
            pk.y = f2b(g1 * sigm(g2));
            g1 = acc1[mf][nf][2]*inv + c1[2]; g2 = acc2[mf][nf][2]*inv + c2[2];
            pk.z = f2b(g1 * sigm(g2));
            g1 = acc1[mf][nf][3]*inv + c1[3]; g2 = acc2[mf][nf][3]*inv + c2[3];
            pk.w = f2b(g1 * sigm(g2));
            *(ushort4*)&G[yo] = pk;
        }
    }
}

// ---------------------------------------------------------------------------
// K8: out[b][c][n] = (x2[b][n][c] - m2)/sd2   (normalize + transpose to f32)
// ---------------------------------------------------------------------------
__global__ __launch_bounds__(256) void k_lnfin(const unsigned short* __restrict__ x2,
                                               const float* __restrict__ st,
                                               float* __restrict__ out)
{
    __shared__ unsigned short ts[64*136];
    const int b = blockIdx.x >> 5, n0 = (blockIdx.x & 31) * 64;
    const float mean = st[2*b] * RCN;
    const float var = st[2*b+1] * RCN - mean * mean;
    const float inv = rsqrtf(var + EPSf);
    const int tid = threadIdx.x;
    {
        const int n = tid >> 2, qd = tid & 3;
        const unsigned short* src = x2 + ((size_t)b * NN + n0 + n) * CC + qd * 32;
        uint4 a0 = *(const uint4*)(src);
        uint4 a1 = *(const uint4*)(src + 8);
        uint4 a2 = *(const uint4*)(src + 16);
        uint4 a3 = *(const uint4*)(src + 24);
        unsigned short* d = &ts[n*136 + qd*32];
        *(uint4*)(d) = a0; *(uint4*)(d+8) = a1; *(uint4*)(d+16) = a2; *(uint4*)(d+24) = a3;
    }
    __syncthreads();
    {
        const int c = tid >> 1, nh = tid & 1;
        float* op = out + ((size_t)b * CC + c) * NN + n0 + nh * 32;
        f32x4 buf;
#pragma unroll
        for (int j = 0; j < 32; j++) {
            buf[j & 3] = (b2f(ts[(nh*32 + j)*136 + c]) - mean) * inv;
            if ((j & 3) == 3) *(f32x4*)(op + (j - 3)) = buf;
        }
    }
}

// ---------------------------------------------------------------------------
extern "C" void kernel_launch(void* const* d_in, const int* in_sizes, int n_in,
                              void* d_out, int out_size, void* d_ws, size_t ws_size,
                              hipStream_t stream)
{
    const float* input = (const float*)d_in[0];
    const float* Wq  = (const float*)d_in[1];
    const float* bq  = (const float*)d_in[2];
    const float* Wv  = (const float*)d_in[3];
    const float* bv  = (const float*)d_in[4];
    const float* Wc  = (const float*)d_in[5];
    const float* bc  = (const float*)d_in[6];
    const float* mem = (const float*)d_in[7];
    const float* saw = (const float*)d_in[8];
    const float* sab = (const float*)d_in[9];
    // nodevec1/2 (d_in[10..11]) provably unused: attn_dyn == value exactly.
    const float* Wg1 = (const float*)d_in[12];
    const float* bg1 = (const float*)d_in[13];
    const float* Wg2 = (const float*)d_in[14];
    const float* bg2 = (const float*)d_in[15];
    const float* Wg3 = (const float*)d_in[16];
    const float* bg3 = (const float*)d_in[17];
    float* out = (float*)d_out;

    unsigned char* wsb = (unsigned char*)d_ws;
    unsigned short* qT  = (unsigned short*)(wsb);                       // 16.78 MB
    unsigned short* vT  = (unsigned short*)(wsb + 16777216);            // 16.78 MB
    unsigned short* ksT = (unsigned short*)(wsb + 2*16777216);          // 512 KB
    float* kvb   = (float*)(wsb + 2*16777216 + 524288);                 // 256 KB
    float* stats = (float*)(wsb + 2*16777216 + 524288 + 262144);        // 512 B

    hipMemsetAsync(kvb, 0, 262144 + 512, stream);

    k_keysm<<<64,   256, 0, stream>>>(mem, ksT);
    k_qv   <<<512,  256, 0, stream>>>(input, Wq, bq, Wv, bv, qT, vT);
    k_kv   <<<256,  256, 0, stream>>>(ksT, vT, kvb);
    k_attn <<<2048, 256, 0, stream>>>(qT, vT, kvb);
    // y1 -> vT ; stats1 -> stats[0..63]
    k_gemmC<0><<<512, 256, 0, stream>>>(qT, Wc, bc, saw, sab, input,
                                        nullptr, nullptr, stats, vT);
    // G -> qT (reads y1=vT with LN folded into weights)
    k_glu12<<<512, 256, 0, stream>>>(vT, Wg1, bg1, Wg2, bg2, stats, qT);
    // x2 -> vT (in-place over y1; per-lane read-then-write), stats2 -> stats[64..127]
    k_gemmC<1><<<512, 256, 0, stream>>>(qT, Wg3, bg3, saw, sab, nullptr,
                                        vT, stats, stats + 64, vT);
    k_lnfin<<<1024, 256, 0, stream>>>(vT, stats + 64, out);
}

// Round 3
// 135.359 us; speedup vs baseline: 1.9616x; 1.0625x over previous
//
#include <hip/hip_runtime.h>
#include <hip/hip_bf16.h>
#include <math.h>

#define DI __device__ __forceinline__

typedef short bf16x8 __attribute__((ext_vector_type(8)));
typedef float f32x4 __attribute__((ext_vector_type(4)));

constexpr int BB = 32, CC = 128, NN = 2048;
constexpr float EPSf = 1e-5f;
constexpr float RCN = 1.0f / (CC * (float)NN);

#define MFMA(a,b,c) __builtin_amdgcn_mfma_f32_16x16x32_bf16(a,b,c,0,0,0)

DI unsigned short f2b(float f){
    union { __hip_bfloat16 h; unsigned short u; } v;
    v.h = __float2bfloat16(f);
    return v.u;
}
DI float b2f(unsigned short h){
    union { unsigned u; float f; } v; v.u = ((unsigned)h) << 16;
    return v.f;
}
DI float sigm(float x){ return 1.0f / (1.0f + __expf(-x)); }

// ---------------------------------------------------------------------------
// K0: one-time weight prep: 6x f32[128x128] -> bf16; rowsums of Wg1/Wg2 (f32)
// ---------------------------------------------------------------------------
__global__ __launch_bounds__(256) void k_prep(
    const float* __restrict__ Wq, const float* __restrict__ Wv,
    const float* __restrict__ Wc, const float* __restrict__ Wg1,
    const float* __restrict__ Wg2, const float* __restrict__ Wg3,
    unsigned short* __restrict__ Wb, float* __restrict__ rs)
{
    const int tid = threadIdx.x;
    if (blockIdx.x < 96) {
        const int i = blockIdx.x * 256 + tid;
        const int m = i >> 12, q = i & 4095;
        const float* src = (m==0)?Wq:(m==1)?Wv:(m==2)?Wc:(m==3)?Wg1:(m==4)?Wg2:Wg3;
        f32x4 w = *(const f32x4*)&src[q * 4];
        ushort4 p; p.x=f2b(w[0]); p.y=f2b(w[1]); p.z=f2b(w[2]); p.w=f2b(w[3]);
        *(ushort4*)&Wb[(size_t)m * 16384 + q * 4] = p;
    } else {
        const float* src = (tid < 128) ? Wg1 : Wg2;
        const int o = tid & 127;
        float s = 0.f;
#pragma unroll
        for (int j = 0; j < 32; j++) {
            f32x4 a = *(const f32x4*)&src[o * 128 + j * 4];
            s += a[0] + a[1] + a[2] + a[3];
        }
        rs[tid] = s;
    }
}

// ---------------------------------------------------------------------------
// K1: ksT[h][x][n] = softmax_x(memory[h,0,n,:]/4)  transposed, bf16
// ---------------------------------------------------------------------------
__global__ __launch_bounds__(256) void k_keysm(const float* __restrict__ mem,
                                               unsigned short* __restrict__ ksT)
{
    const int row = blockIdx.x * 256 + threadIdx.x;   // h*NN + n
    const int h = row >> 11, n = row & 2047;
    const float* p = mem + (size_t)row * 16;
    float v[16];
    f32x4 t0 = *(const f32x4*)(p);
    f32x4 t1 = *(const f32x4*)(p + 4);
    f32x4 t2 = *(const f32x4*)(p + 8);
    f32x4 t3 = *(const f32x4*)(p + 12);
#pragma unroll
    for (int j = 0; j < 4; j++) { v[j]=t0[j]; v[4+j]=t1[j]; v[8+j]=t2[j]; v[12+j]=t3[j]; }
    float mx = v[0];
#pragma unroll
    for (int x = 1; x < 16; x++) mx = fmaxf(mx, v[x]);
    float s = 0.f;
#pragma unroll
    for (int x = 0; x < 16; x++) { v[x] = __expf((v[x] - mx) * 0.25f); s += v[x]; }
    const float is = 1.0f / s;
#pragma unroll
    for (int x = 0; x < 16; x++)
        ksT[((size_t)(h * 16 + x)) * NN + n] = f2b(v[x] * is);
}

// ---------------------------------------------------------------------------
// K2: fused Q,V GEMM (LDS-free). qT/vT[b][n][c] bf16 = relu(W X + b)
// ---------------------------------------------------------------------------
__global__ __launch_bounds__(256,2) void k_qv(
    const float* __restrict__ in, const unsigned short* __restrict__ WqB,
    const unsigned short* __restrict__ WvB, const float* __restrict__ bq,
    const float* __restrict__ bv, unsigned short* __restrict__ qT,
    unsigned short* __restrict__ vT)
{
    const int b = blockIdx.x >> 4, n0 = (blockIdx.x & 15) * 128;
    const int tid = threadIdx.x, l = tid & 63, wid = tid >> 6;
    const int wo = wid & 1, wn = wid >> 1, lr = l & 15, lg = l >> 4;
    f32x4 accq[4][4], accv[4][4];
    const f32x4 z = {0.f,0.f,0.f,0.f};
#pragma unroll
    for (int i = 0; i < 4; i++)
#pragma unroll
        for (int j = 0; j < 4; j++) { accq[i][j] = z; accv[i][j] = z; }
    const float* inb = in + (size_t)b * CC * NN;
#pragma unroll
    for (int ks = 0; ks < 4; ks++) {
        const int cb = ks * 32 + lg * 8;
        bf16x8 aq[4], av[4];
#pragma unroll
        for (int mf = 0; mf < 4; mf++) {
            const int o = wo*64 + mf*16 + lr;
            aq[mf] = *(const bf16x8*)&WqB[o * 128 + cb];
            av[mf] = *(const bf16x8*)&WvB[o * 128 + cb];
        }
        bf16x8 bx[4];
#pragma unroll
        for (int nf = 0; nf < 4; nf++) {
            const int n = n0 + wn*64 + nf*16 + lr;
            union { bf16x8 v; unsigned short u[8]; } t;
#pragma unroll
            for (int j = 0; j < 8; j++) t.u[j] = f2b(inb[(size_t)(cb + j) * NN + n]);
            bx[nf] = t.v;
        }
#pragma unroll
        for (int mf = 0; mf < 4; mf++)
#pragma unroll
            for (int nf = 0; nf < 4; nf++) {
                accq[mf][nf] = MFMA(aq[mf], bx[nf], accq[mf][nf]);
                accv[mf][nf] = MFMA(av[mf], bx[nf], accv[mf][nf]);
            }
    }
#pragma unroll
    for (int mf = 0; mf < 4; mf++) {
        const int ob = wo*64 + mf*16 + lg*4;
        const f32x4 bq4 = *(const f32x4*)&bq[ob];
        const f32x4 bv4 = *(const f32x4*)&bv[ob];
#pragma unroll
        for (int nf = 0; nf < 4; nf++) {
            const int n = n0 + wn*64 + nf*16 + lr;
            const size_t yo = ((size_t)b * NN + n) * CC + ob;
            f32x4 aq_ = accq[mf][nf], av_ = accv[mf][nf];
            ushort4 pq, pv;
            pq.x = f2b(fmaxf(aq_[0]+bq4[0],0.f)); pq.y = f2b(fmaxf(aq_[1]+bq4[1],0.f));
            pq.z = f2b(fmaxf(aq_[2]+bq4[2],0.f)); pq.w = f2b(fmaxf(aq_[3]+bq4[3],0.f));
            pv.x = f2b(fmaxf(av_[0]+bv4[0],0.f)); pv.y = f2b(fmaxf(av_[1]+bv4[1],0.f));
            pv.z = f2b(fmaxf(av_[2]+bv4[2],0.f)); pv.w = f2b(fmaxf(av_[3]+bv4[3],0.f));
            *(ushort4*)&qT[yo] = pq;
            *(ushort4*)&vT[yo] = pv;
        }
    }
}

// ---------------------------------------------------------------------------
// K3: kv[b,h] = sum_n ksT[h,:,n] x vT[b,n,h16+:]  (no atomics: LDS reduce)
// ---------------------------------------------------------------------------
__global__ __launch_bounds__(256) void k_kv(const unsigned short* __restrict__ ksT,
                                            const unsigned short* __restrict__ vT,
                                            float* __restrict__ kvb)
{
    __shared__ unsigned short vt[4 * 16 * 520];
    __shared__ float red[1024];
    const int b = blockIdx.x >> 3, h = blockIdx.x & 7;
    const int tid = threadIdx.x, l = tid & 63, wid = tid >> 6;
    const int n0 = wid * 512;
    unsigned short* vtw = vt + wid * (16 * 520);
    const unsigned short* vb = vT + ((size_t)b * NN + n0) * CC + h * 16;
#pragma unroll
    for (int r = 0; r < 8; r++) {
        const int nl = r * 64 + l;
        ushort4 p0 = *(const ushort4*)&vb[(size_t)nl * CC + 0];
        ushort4 p1 = *(const ushort4*)&vb[(size_t)nl * CC + 4];
        ushort4 p2 = *(const ushort4*)&vb[(size_t)nl * CC + 8];
        ushort4 p3 = *(const ushort4*)&vb[(size_t)nl * CC + 12];
        vtw[ 0*520+nl]=p0.x; vtw[ 1*520+nl]=p0.y; vtw[ 2*520+nl]=p0.z; vtw[ 3*520+nl]=p0.w;
        vtw[ 4*520+nl]=p1.x; vtw[ 5*520+nl]=p1.y; vtw[ 6*520+nl]=p1.z; vtw[ 7*520+nl]=p1.w;
        vtw[ 8*520+nl]=p2.x; vtw[ 9*520+nl]=p2.y; vtw[10*520+nl]=p2.z; vtw[11*520+nl]=p2.w;
        vtw[12*520+nl]=p3.x; vtw[13*520+nl]=p3.y; vtw[14*520+nl]=p3.z; vtw[15*520+nl]=p3.w;
    }
    const int lr = l & 15, lg = l >> 4;
    const unsigned short* ka = ksT + (size_t)h * 16 * NN;
    f32x4 acc = {0.f,0.f,0.f,0.f};
#pragma unroll
    for (int kk = 0; kk < 16; kk++) {
        bf16x8 af = *(const bf16x8*)&ka[(size_t)lr * NN + n0 + kk*32 + lg*8];
        bf16x8 bf = *(const bf16x8*)&vtw[lr * 520 + kk*32 + lg*8];
        acc = MFMA(af, bf, acc);
    }
#pragma unroll
    for (int r = 0; r < 4; r++)
        red[wid * 256 + (lg*4 + r) * 16 + lr] = acc[r];
    __syncthreads();
    {
        const float s = red[tid] + red[256 + tid] + red[512 + tid] + red[768 + tid];
        kvb[((size_t)(b * 8 + h)) * 256 + tid] = s;
    }
}

// ---------------------------------------------------------------------------
// K4: fused attention + Wc GEMM + affine/residual epilogue.
//  phase A: xcat[n][c] = softmax(q/4).kv + v  -> LDS
//  phase B: y1 = relu(Wc.xcat + bc); y = y1*sw+sb+y1+input; partial stats
// ---------------------------------------------------------------------------
__global__ __launch_bounds__(256,2) void k_attnC(
    const unsigned short* __restrict__ qT, unsigned short* __restrict__ vT,
    const float* __restrict__ kvb, const unsigned short* __restrict__ WcB,
    const float* __restrict__ bc, const float* __restrict__ saw,
    const float* __restrict__ sab, const float* __restrict__ in0f,
    float* __restrict__ part1)
{
    __shared__ float kvl[8 * 260];
    __shared__ unsigned short xc[128 * 136];
    __shared__ float red[8];
    const int b = blockIdx.x >> 4, n0 = (blockIdx.x & 15) * 128;
    const int tid = threadIdx.x;
    {
        const float* kp = kvb + (size_t)b * 2048 + (tid >> 5) * 256 + (tid & 31) * 8;
        f32x4 v0 = *(const f32x4*)kp;
        f32x4 v1 = *(const f32x4*)(kp + 4);
        float* dst = &kvl[(tid >> 5) * 260 + (tid & 31) * 8];
        *(f32x4*)dst = v0; *(f32x4*)(dst + 4) = v1;
    }
    __syncthreads();
#pragma unroll
    for (int it = 0; it < 4; it++) {
        const int idx = it * 256 + tid;
        const int nl = idx >> 3, h = idx & 7;
        const size_t base = ((size_t)b * NN + n0 + nl) * CC + h * 16;
        const unsigned short* qp = qT + base;
        const unsigned short* vp = vT + base;
        float q[16];
        {
            uint4 u0 = *(const uint4*)qp, u1 = *(const uint4*)(qp + 8);
            unsigned uu[8] = {u0.x,u0.y,u0.z,u0.w,u1.x,u1.y,u1.z,u1.w};
#pragma unroll
            for (int j = 0; j < 8; j++) {
                q[2*j]   = b2f((unsigned short)(uu[j] & 0xffffu));
                q[2*j+1] = b2f((unsigned short)(uu[j] >> 16));
            }
        }
        float mx = q[0];
#pragma unroll
        for (int x = 1; x < 16; x++) mx = fmaxf(mx, q[x]);
        float p[16]; float s = 0.f;
#pragma unroll
        for (int x = 0; x < 16; x++) { p[x] = __expf((q[x] - mx) * 0.25f); s += p[x]; }
        const float is = 1.0f / s;
        const float* kh = &kvl[h * 260];
        float r[16];
#pragma unroll
        for (int y = 0; y < 16; y++) r[y] = 0.f;
#pragma unroll
        for (int x = 0; x < 16; x++) {
            const float px = p[x];
#pragma unroll
            for (int y = 0; y < 16; y++) r[y] = fmaf(px, kh[x * 16 + y], r[y]);
        }
        uint4 w0 = *(const uint4*)vp, w1 = *(const uint4*)(vp + 8);
        unsigned vv[8] = {w0.x,w0.y,w0.z,w0.w,w1.x,w1.y,w1.z,w1.w};
        unsigned short* xp = &xc[nl * 136 + h * 16];
#pragma unroll
        for (int j2 = 0; j2 < 4; j2++) {
            ushort4 pk;
            pk.x = f2b(r[4*j2+0]*is + b2f((unsigned short)(vv[2*j2]   & 0xffffu)));
            pk.y = f2b(r[4*j2+1]*is + b2f((unsigned short)(vv[2*j2]   >> 16)));
            pk.z = f2b(r[4*j2+2]*is + b2f((unsigned short)(vv[2*j2+1] & 0xffffu)));
            pk.w = f2b(r[4*j2+3]*is + b2f((unsigned short)(vv[2*j2+1] >> 16)));
            *(ushort4*)&xp[j2 * 4] = pk;
        }
    }
    __syncthreads();
    const int l = tid & 63, wid = tid >> 6;
    const int wo = wid & 1, wn = wid >> 1, lr = l & 15, lg = l >> 4;
    f32x4 acc[4][4];
    const f32x4 z = {0.f,0.f,0.f,0.f};
#pragma unroll
    for (int i = 0; i < 4; i++)
#pragma unroll
        for (int j = 0; j < 4; j++) acc[i][j] = z;
#pragma unroll
    for (int ks = 0; ks < 4; ks++) {
        const int cb = ks * 32 + lg * 8;
        bf16x8 af[4];
#pragma unroll
        for (int mf = 0; mf < 4; mf++)
            af[mf] = *(const bf16x8*)&WcB[(wo*64 + mf*16 + lr) * 128 + cb];
        bf16x8 bx[4];
#pragma unroll
        for (int nf = 0; nf < 4; nf++)
            bx[nf] = *(const bf16x8*)&xc[(wn*64 + nf*16 + lr) * 136 + cb];
#pragma unroll
        for (int mf = 0; mf < 4; mf++)
#pragma unroll
            for (int nf = 0; nf < 4; nf++)
                acc[mf][nf] = MFMA(af[mf], bx[nf], acc[mf][nf]);
    }
    float sum = 0.f, ssq = 0.f;
#pragma unroll
    for (int mf = 0; mf < 4; mf++) {
        const int ob = wo*64 + mf*16 + lg*4;
        const f32x4 b4 = *(const f32x4*)&bc[ob];
#pragma unroll
        for (int nf = 0; nf < 4; nf++) {
            const int n = n0 + wn*64 + nf*16 + lr;
            const size_t yo = ((size_t)b * NN + n) * CC + ob;
            f32x4 a = acc[mf][nf];
            float ys[4];
#pragma unroll
            for (int r = 0; r < 4; r++) {
                const int o = ob + r;
                const float t = fmaxf(a[r] + b4[r], 0.f);
                const float sw = saw[(size_t)o * NN + n];
                const float sb = sab[(size_t)o * NN + n];
                float y = t * sw + sb + t + in0f[((size_t)b * CC + o) * NN + n];
                sum += y; ssq += y * y;
                ys[r] = y;
            }
            ushort4 pk;
            pk.x = f2b(ys[0]); pk.y = f2b(ys[1]); pk.z = f2b(ys[2]); pk.w = f2b(ys[3]);
            *(ushort4*)&vT[yo] = pk;
        }
    }
#pragma unroll
    for (int off = 32; off > 0; off >>= 1) {
        sum += __shfl_down(sum, off);
        ssq += __shfl_down(ssq, off);
    }
    if ((tid & 63) == 0) { red[wid*2] = sum; red[wid*2+1] = ssq; }
    __syncthreads();
    if (tid == 0) {
        part1[2 * blockIdx.x]     = red[0]+red[2]+red[4]+red[6];
        part1[2 * blockIdx.x + 1] = red[1]+red[3]+red[5]+red[7];
    }
}

// ---------------------------------------------------------------------------
// K5: fused GLU(Wg1,Wg2 with LN folded) + Wg3 GEMM + residual/affine epilogue.
// ---------------------------------------------------------------------------
__global__ __launch_bounds__(256,2) void k_glu3(
    const unsigned short* __restrict__ y1,
    const unsigned short* __restrict__ W1B, const unsigned short* __restrict__ W2B,
    const unsigned short* __restrict__ W3B,
    const float* __restrict__ b1, const float* __restrict__ b2,
    const float* __restrict__ b3, const float* __restrict__ rs,
    const float* __restrict__ part1, const float* __restrict__ saw,
    const float* __restrict__ sab, unsigned short* __restrict__ X2,
    float* __restrict__ part2)
{
    __shared__ unsigned short yt[128 * 136];
    __shared__ unsigned short gx[128 * 136];
    __shared__ float cs[256];
    __shared__ float red[8];
    const int b = blockIdx.x >> 4, n0 = (blockIdx.x & 15) * 128;
    const int tid = threadIdx.x;
    float s0 = 0.f, q0 = 0.f;
#pragma unroll
    for (int t = 0; t < 16; t++) { s0 += part1[(b*16+t)*2]; q0 += part1[(b*16+t)*2+1]; }
    const float mean = s0 * RCN;
    const float var  = q0 * RCN - mean * mean;
    const float inv  = rsqrtf(var + EPSf);
    {
        const int cq = tid & 15;
#pragma unroll
        for (int it = 0; it < 8; it++) {
            const int n = it * 16 + (tid >> 4);
            uint4 u = *(const uint4*)&y1[((size_t)b * NN + n0 + n) * CC + cq * 8];
            *(uint4*)&yt[n * 136 + cq * 8] = u;
        }
    }
    {
        const int o = tid & 127;
        const float bb = (tid < 128) ? b1[o] : b2[o];
        cs[tid] = bb - mean * inv * rs[tid];
    }
    __syncthreads();
    const int l = tid & 63, wid = tid >> 6;
    const int wo = wid & 1, wn = wid >> 1, lr = l & 15, lg = l >> 4;
    {
        f32x4 acc1[4][4], acc2[4][4];
        const f32x4 z = {0.f,0.f,0.f,0.f};
#pragma unroll
        for (int i = 0; i < 4; i++)
#pragma unroll
            for (int j = 0; j < 4; j++) { acc1[i][j] = z; acc2[i][j] = z; }
#pragma unroll
        for (int ks = 0; ks < 4; ks++) {
            const int cb = ks * 32 + lg * 8;
            bf16x8 a1[4], a2[4];
#pragma unroll
            for (int mf = 0; mf < 4; mf++) {
                const int o = wo*64 + mf*16 + lr;
                a1[mf] = *(const bf16x8*)&W1B[o * 128 + cb];
                a2[mf] = *(const bf16x8*)&W2B[o * 128 + cb];
            }
            bf16x8 bx[4];
#pragma unroll
            for (int nf = 0; nf < 4; nf++)
                bx[nf] = *(const bf16x8*)&yt[(wn*64 + nf*16 + lr) * 136 + cb];
#pragma unroll
            for (int mf = 0; mf < 4; mf++)
#pragma unroll
                for (int nf = 0; nf < 4; nf++) {
                    acc1[mf][nf] = MFMA(a1[mf], bx[nf], acc1[mf][nf]);
                    acc2[mf][nf] = MFMA(a2[mf], bx[nf], acc2[mf][nf]);
                }
        }
#pragma unroll
        for (int mf = 0; mf < 4; mf++) {
            const int ob = wo*64 + mf*16 + lg*4;
            const f32x4 c1 = *(const f32x4*)&cs[ob];
            const f32x4 c2 = *(const f32x4*)&cs[128 + ob];
#pragma unroll
            for (int nf = 0; nf < 4; nf++) {
                const int nl = wn*64 + nf*16 + lr;
                ushort4 pk;
                float g1, g2;
                g1 = acc1[mf][nf][0]*inv + c1[0]; g2 = acc2[mf][nf][0]*inv + c2[0];
                pk.x = f2b(g1 * sigm(g2));
                g1 = acc1[mf][nf][1]*inv + c1[1]; g2 = acc2[mf][nf][1]*inv + c2[1];
                pk.y = f2b(g1 * sigm(g2));
                g1 = acc1[mf][nf][2]*inv + c1[2]; g2 = acc2[mf][nf][2]*inv + c2[2];
                pk.z = f2b(g1 * sigm(g2));
                g1 = acc1[mf][nf][3]*inv + c1[3]; g2 = acc2[mf][nf][3]*inv + c2[3];
                pk.w = f2b(g1 * sigm(g2));
                *(ushort4*)&gx[nl * 136 + ob] = pk;
            }
        }
    }
    __syncthreads();
    f32x4 acc[4][4];
    const f32x4 z = {0.f,0.f,0.f,0.f};
#pragma unroll
    for (int i = 0; i < 4; i++)
#pragma unroll
        for (int j = 0; j < 4; j++) acc[i][j] = z;
#pragma unroll
    for (int ks = 0; ks < 4; ks++) {
        const int cb = ks * 32 + lg * 8;
        bf16x8 af[4];
#pragma unroll
        for (int mf = 0; mf < 4; mf++)
            af[mf] = *(const bf16x8*)&W3B[(wo*64 + mf*16 + lr) * 128 + cb];
        bf16x8 bx[4];
#pragma unroll
        for (int nf = 0; nf < 4; nf++)
            bx[nf] = *(const bf16x8*)&gx[(wn*64 + nf*16 + lr) * 136 + cb];
#pragma unroll
        for (int mf = 0; mf < 4; mf++)
#pragma unroll
            for (int nf = 0; nf < 4; nf++)
                acc[mf][nf] = MFMA(af[mf], bx[nf], acc[mf][nf]);
    }
    float sum = 0.f, ssq = 0.f;
#pragma unroll
    for (int mf = 0; mf < 4; mf++) {
        const int ob = wo*64 + mf*16 + lg*4;
        const f32x4 b4 = *(const f32x4*)&b3[ob];
#pragma unroll
        for (int nf = 0; nf < 4; nf++) {
            const int nl = wn*64 + nf*16 + lr;
            const int n = n0 + nl;
            const size_t yo = ((size_t)b * NN + n) * CC + ob;
            ushort4 yq = *(const ushort4*)&yt[nl * 136 + ob];
            f32x4 a = acc[mf][nf];
            float ys[4];
#pragma unroll
            for (int r = 0; r < 4; r++) {
                const int o = ob + r;
                const unsigned short ev = (r==0)?yq.x:(r==1)?yq.y:(r==2)?yq.z:yq.w;
                const float t = a[r] + b4[r] + (b2f(ev) - mean) * inv;
                const float sw = saw[(size_t)o * NN + n];
                const float sb = sab[(size_t)o * NN + n];
                const float y = t * sw + sb + t;
                sum += y; ssq += y * y;
                ys[r] = y;
            }
            ushort4 pk;
            pk.x = f2b(ys[0]); pk.y = f2b(ys[1]); pk.z = f2b(ys[2]); pk.w = f2b(ys[3]);
            *(ushort4*)&X2[yo] = pk;
        }
    }
#pragma unroll
    for (int off = 32; off > 0; off >>= 1) {
        sum += __shfl_down(sum, off);
        ssq += __shfl_down(ssq, off);
    }
    if ((tid & 63) == 0) { red[wid*2] = sum; red[wid*2+1] = ssq; }
    __syncthreads();
    if (tid == 0) {
        part2[2 * blockIdx.x]     = red[0]+red[2]+red[4]+red[6];
        part2[2 * blockIdx.x + 1] = red[1]+red[3]+red[5]+red[7];
    }
}

// ---------------------------------------------------------------------------
// K6: out[b][c][n] = (x2[b][n][c] - m2)/sd2  — coalesced stores via LDS transpose
// ---------------------------------------------------------------------------
__global__ __launch_bounds__(256) void k_lnfin(const unsigned short* __restrict__ x2,
                                               const float* __restrict__ part2,
                                               float* __restrict__ out)
{
    __shared__ unsigned ts[64 * 69];   // [cpair][n+pad]
    const int b = blockIdx.x >> 5, n0 = (blockIdx.x & 31) * 64;
    const int tid = threadIdx.x;
    float s0 = 0.f, q0 = 0.f;
#pragma unroll
    for (int t = 0; t < 16; t++) { s0 += part2[(b*16+t)*2]; q0 += part2[(b*16+t)*2+1]; }
    const float mean = s0 * RCN;
    const float var  = q0 * RCN - mean * mean;
    const float inv  = rsqrtf(var + EPSf);
    {
        const int n = tid >> 2, qd = tid & 3;
        const unsigned short* src = x2 + ((size_t)b * NN + n0 + n) * CC + qd * 32;
        uint4 a0 = *(const uint4*)(src);
        uint4 a1 = *(const uint4*)(src + 8);
        uint4 a2 = *(const uint4*)(src + 16);
        uint4 a3 = *(const uint4*)(src + 24);
        unsigned u[16] = {a0.x,a0.y,a0.z,a0.w, a1.x,a1.y,a1.z,a1.w,
                          a2.x,a2.y,a2.z,a2.w, a3.x,a3.y,a3.z,a3.w};
#pragma unroll
        for (int k = 0; k < 16; k++)
            ts[(qd * 16 + k) * 69 + n] = u[k];
    }
    __syncthreads();
#pragma unroll
    for (int pass = 0; pass < 8; pass++) {
        const int c = pass * 16 + (tid >> 4), nq = tid & 15;
        const int cp = c >> 1, hi = c & 1;
        f32x4 v;
#pragma unroll
        for (int j = 0; j < 4; j++) {
            const unsigned u = ts[cp * 69 + nq * 4 + j];
            const unsigned short hv = hi ? (unsigned short)(u >> 16)
                                         : (unsigned short)(u & 0xffffu);
            v[j] = (b2f(hv) - mean) * inv;
        }
        *(f32x4*)&out[((size_t)b * CC + c) * NN + n0 + nq * 4] = v;
    }
}

// ---------------------------------------------------------------------------
extern "C" void kernel_launch(void* const* d_in, const int* in_sizes, int n_in,
                              void* d_out, int out_size, void* d_ws, size_t ws_size,
                              hipStream_t stream)
{
    const float* input = (const float*)d_in[0];
    const float* Wq  = (const float*)d_in[1];
    const float* bq  = (const float*)d_in[2];
    const float* Wv  = (const float*)d_in[3];
    const float* bv  = (const float*)d_in[4];
    const float* Wc  = (const float*)d_in[5];
    const float* bc  = (const float*)d_in[6];
    const float* mem = (const float*)d_in[7];
    const float* saw = (const float*)d_in[8];
    const float* sab = (const float*)d_in[9];
    // nodevec1/2 (d_in[10..11]) provably unused: attn_dyn == value exactly.
    const float* Wg1 = (const float*)d_in[12];
    const float* bg1 = (const float*)d_in[13];
    const float* Wg2 = (const float*)d_in[14];
    const float* bg2 = (const float*)d_in[15];
    const float* Wg3 = (const float*)d_in[16];
    const float* bg3 = (const float*)d_in[17];
    float* out = (float*)d_out;

    unsigned char* wsb = (unsigned char*)d_ws;
    unsigned short* qT  = (unsigned short*)(wsb);                    // 16.78 MB
    unsigned short* vT  = (unsigned short*)(wsb + 16777216);         // 16.78 MB
    unsigned short* ksT = (unsigned short*)(wsb + 33554432);         // 512 KB
    float* kvb   = (float*)(wsb + 34078720);                         // 256 KB
    unsigned short* Wb  = (unsigned short*)(wsb + 34340864);         // 192 KB
    float* rs    = (float*)(wsb + 34537472);                         // 1 KB
    float* part1 = (float*)(wsb + 34538496);                         // 4 KB
    float* part2 = (float*)(wsb + 34542592);                         // 4 KB

    k_prep <<<97,   256, 0, stream>>>(Wq, Wv, Wc, Wg1, Wg2, Wg3, Wb, rs);
    k_keysm<<<64,   256, 0, stream>>>(mem, ksT);
    k_qv   <<<512,  256, 0, stream>>>(input, Wb, Wb + 16384, bq, bv, qT, vT);
    k_kv   <<<256,  256, 0, stream>>>(ksT, vT, kvb);
    k_attnC<<<512,  256, 0, stream>>>(qT, vT, kvb, Wb + 2*16384, bc, saw, sab,
                                      input, part1);
    k_glu3 <<<512,  256, 0, stream>>>(vT, Wb + 3*16384, Wb + 4*16384, Wb + 5*16384,
                                      bg1, bg2, bg3, rs, part1, saw, sab, qT, part2);
    k_lnfin<<<1024, 256, 0, stream>>>(qT, part2, out);
}